// Round 8
// baseline (787.648 us; speedup 1.0000x reference)
//
#include <hip/hip_runtime.h>

namespace {

constexpr int N = 2048;
constexpr int D = 64;
constexpr float SCALE = 0.125f;   // D^-0.5
constexpr int LK = 72;            // k_s / s_s row stride (shorts): 16B-aligned rows
constexpr int LV = 68;            // vt_s row stride (shorts): 8B-aligned rows
constexpr int NT = N / 64;        // 32 K-tiles; also 32 mask-words per row
constexpr int BH = 32;            // B*H
constexpr size_t NKV    = (size_t)BH * N * D;   // 4.19M elems per K/V tensor
constexpr size_t NMASK  = (size_t)BH * N * N;   // 134.2M mask elems
constexpr size_t NWORDS = NMASK / 64;           // 2.097M uint64 bitmask words

typedef __attribute__((ext_vector_type(8))) short bf16x8;   // MFMA A/B frag
typedef __attribute__((ext_vector_type(4))) short short4v;  // b64 LDS packet
typedef __attribute__((ext_vector_type(2))) short short2v;
typedef __attribute__((ext_vector_type(4))) float f32x4;    // MFMA C/D frag

__device__ inline short f2bf(float x) {
  union { float f; unsigned u; } a; a.f = x;
  unsigned r = a.u + 0x7fffu + ((a.u >> 16) & 1u);
  return (short)(r >> 16);
}

#if __has_builtin(__builtin_amdgcn_cvt_pk_bf16_f32)
typedef __attribute__((ext_vector_type(2))) __bf16 bfv2;
__device__ inline short2v pk_bf(float lo, float hi) {
  bfv2 t = __builtin_amdgcn_cvt_pk_bf16_f32(lo, hi);
  return __builtin_bit_cast(short2v, t);
}
#else
__device__ inline short2v pk_bf(float lo, float hi) {
  short2v r; r[0] = f2bf(lo); r[1] = f2bf(hi); return r;
}
#endif

__device__ inline short4v pk4(float4 f) {
  short2v a = pk_bf(f.x, f.y), b = pk_bf(f.z, f.w);
  short4v r; r[0] = a[0]; r[1] = a[1]; r[2] = b[0]; r[3] = b[1];
  return r;
}

__device__ inline float fast_tanh(float x) {
  // tanh(x) = 1 - 2/(exp2(x*2log2e)+1); correct limits at +-inf
  float e = __builtin_amdgcn_exp2f(x * 2.885390081777927f);
  return 1.0f - 2.0f * __builtin_amdgcn_rcpf(e + 1.0f);
}

} // namespace

// ---- pre-pass 1: K,V fp32 -> bf16 into workspace ----
__global__ __launch_bounds__(256) void cvt_kv_bf16(
    const float* __restrict__ K, const float* __restrict__ V,
    short* __restrict__ KB, short* __restrict__ VB)
{
  const int n4 = (int)(NKV / 4);
  const int stride = gridDim.x * blockDim.x;
  for (int j = blockIdx.x * blockDim.x + threadIdx.x; j < n4; j += stride) {
    ((short4v*)KB)[j] = pk4(((const float4*)K)[j]);
    ((short4v*)VB)[j] = pk4(((const float4*)V)[j]);
  }
}

// ---- pre-pass 2: int32 mask -> 1 bit/elem, pure-streaming at HBM peak ----
// Word w covers elements [w*64, w*64+64); bit l = (elem w*64+l != 0).
// __ballot bit l = lane l, and lane l reads element base+l -> order matches.
// 2048 blocks x 4 waves = 8192 waves x 256 steps x 64 lanes = 134.2M exactly.
__global__ __launch_bounds__(256) void mask_pack(
    const int* __restrict__ M, unsigned long long* __restrict__ W)
{
  const int lane = threadIdx.x & 63;
  const size_t g = (size_t)blockIdx.x * 4 + (threadIdx.x >> 6);   // wave id
  const size_t steps = NWORDS / 8192;                             // 256
  const int* p = M + (g * steps) * 64 + lane;
  unsigned long long* w = W + g * steps;
  for (size_t s = 0; s < steps; s += 8) {
    int v[8];
#pragma unroll
    for (int j = 0; j < 8; ++j)
      v[j] = __builtin_nontemporal_load(p + (s + j) * 64);   // 8 x 256B in flight
    unsigned long long b[8];
#pragma unroll
    for (int j = 0; j < 8; ++j) b[j] = __ballot(v[j] != 0);
    if (lane == 0) {
#pragma unroll
      for (int j = 0; j < 8; ++j) w[s + j] = b[j];
    }
  }
}

// ---- main: one block = one (b,h) x 64-row Q tile; 4 waves of 16 rows ----
// bh = blk&31 (XCD-affine: bf16 K/V stay in that XCD's L2). Mask arrives as
// 1 uint64/row/tile (8B; consecutive kt share a cache line -> L1-hot).
__global__ __launch_bounds__(256, 4) void attn_tanh_kernel(
    const float* __restrict__ Q, const short* __restrict__ KB,
    const short* __restrict__ VB, const unsigned long long* __restrict__ MW,
    float* __restrict__ O)
{
  __shared__ __align__(16) short k_s[64 * LK];
  __shared__ __align__(16) short s_s[64 * LK];
  __shared__ __align__(16) short vt_s[64 * LV];   // V transposed: [d][kpos]

  const int tid  = threadIdx.x;
  const int wave = tid >> 6;
  const int lane = tid & 63;
  const int l15  = lane & 15;
  const int quad = lane >> 4;

  const int bh = blockIdx.x & 31;
  const int q0 = (blockIdx.x >> 5) * 64;

  const float* qp = Q + (size_t)bh * N * D;
  float* op = O + (size_t)bh * N * D;
  const short* kpb = KB + (size_t)bh * N * D;
  const short* vpb = VB + (size_t)bh * N * D;
  const short* vbase = vpb + (size_t)(wave * 16) * D + lane;   // lane = d
  const unsigned long long* mwb =
      MW + ((size_t)bh * N + q0 + wave * 16 + l15) * NT;       // 32 words/row

  // ---- Q B-fragments in registers for all 32 tiles ----
  bf16x8 qf[2];
  {
    const float* qrow = qp + (size_t)(q0 + wave * 16 + l15) * D + quad * 8;
#pragma unroll
    for (int ks = 0; ks < 2; ++ks) {
      float4 f0 = *(const float4*)(qrow + ks * 32);
      float4 f1 = *(const float4*)(qrow + ks * 32 + 4);
      short4v lo = pk4(f0), hi = pk4(f1);
      bf16x8 t;
      t[0]=lo[0]; t[1]=lo[1]; t[2]=lo[2]; t[3]=lo[3];
      t[4]=hi[0]; t[5]=hi[1]; t[6]=hi[2]; t[7]=hi[3];
      qf[ks] = t;
    }
  }

  const int krow = tid >> 3;         // K staging row 0..31 (+32 via i)
  const int kcol = (tid & 7) * 8;    // 16B slots
  bf16x8 kreg2[2];
  short  vregb[16];
  unsigned long long mreg;

  auto issue_loads = [&](int kt1) {
    const short* kt_ = kpb + (size_t)kt1 * 64 * D;
#pragma unroll
    for (int i = 0; i < 2; ++i)
      kreg2[i] = *(const bf16x8*)(kt_ + (size_t)(krow + i * 32) * D + kcol);
    const short* vt_ = vbase + (size_t)kt1 * 64 * D;
#pragma unroll
    for (int i = 0; i < 16; ++i)
      vregb[i] = vt_[(size_t)i * D];
    mreg = mwb[kt1];
  };

  auto write_kv = [&]() {
#pragma unroll
    for (int i = 0; i < 2; ++i)
      *(bf16x8*)(&k_s[(krow + i * 32) * LK + kcol]) = kreg2[i];
#pragma unroll
    for (int c = 0; c < 4; ++c) {
      short4v vv;
      vv[0] = vregb[4*c+0]; vv[1] = vregb[4*c+1];
      vv[2] = vregb[4*c+2]; vv[3] = vregb[4*c+3];
      *(short4v*)(&vt_s[lane * LV + wave * 16 + 4 * c]) = vv;
    }
  };

  issue_loads(0);

  f32x4 o_acc[4];
#pragma unroll
  for (int i = 0; i < 4; ++i) o_acc[i] = (f32x4){0.f, 0.f, 0.f, 0.f};

  for (int kt = 0; kt < NT; ++kt) {
    __syncthreads();   // previous tile's k_s/vt_s readers done
    write_kv();
    __syncthreads();

    const unsigned long long mcur = mreg;

    // ---- S^T = K Q^T (operand swap), tanh, mask-bit select; b64 S write ----
#pragma unroll
    for (int ct = 0; ct < 4; ++ct) {
      f32x4 acc = {0.f, 0.f, 0.f, 0.f};
#pragma unroll
      for (int ksi = 0; ksi < 2; ++ksi) {
        bf16x8 a = *(const bf16x8*)(&k_s[(ct * 16 + l15) * LK + ksi * 32 + quad * 8]);
        acc = __builtin_amdgcn_mfma_f32_16x16x32_bf16(a, qf[ksi], acc, 0, 0, 0);
      }
      // C layout of S^T: lane(quad,l15) reg r = S[q=l15][kp=ct*16+quad*4+r]
      const unsigned mn = (unsigned)(mcur >> (ct * 16 + quad * 4)) & 0xFu;
      float s0 = (mn & 1u) ? 0.f : fast_tanh(acc[0] * SCALE);
      float s1 = (mn & 2u) ? 0.f : fast_tanh(acc[1] * SCALE);
      float s2 = (mn & 4u) ? 0.f : fast_tanh(acc[2] * SCALE);
      float s3 = (mn & 8u) ? 0.f : fast_tanh(acc[3] * SCALE);
      short2v p0 = pk_bf(s0, s1), p1 = pk_bf(s2, s3);
      short4v sv; sv[0]=p0[0]; sv[1]=p0[1]; sv[2]=p1[0]; sv[3]=p1[1];
      *(short4v*)(&s_s[(wave * 16 + l15) * LK + ct * 16 + quad * 4]) = sv;
    }

    // ---- prefetch tile kt+1 (issue only; consumed next iteration) ----
    if (kt + 1 < NT) issue_loads(kt + 1);

    // ---- O += S V  (s_s is wave-local: no barrier needed) ----
#pragma unroll
    for (int ksi = 0; ksi < 2; ++ksi) {
      bf16x8 a = *(const bf16x8*)(&s_s[(wave * 16 + l15) * LK + ksi * 32 + quad * 8]);
#pragma unroll
      for (int nt = 0; nt < 4; ++nt) {
        const short* vb = &vt_s[(nt * 16 + l15) * LV + ksi * 32 + quad * 8];
        short4v lo = *(const short4v*)(vb);
        short4v hi = *(const short4v*)(vb + 4);
        bf16x8 b = __builtin_shufflevector(lo, hi, 0, 1, 2, 3, 4, 5, 6, 7);
        o_acc[nt] = __builtin_amdgcn_mfma_f32_16x16x32_bf16(a, b, o_acc[nt], 0, 0, 0);
      }
    }
  }

  // ---- write O (C layout: row q = quad*4+r, col d = nt*16+l15) ----
#pragma unroll
  for (int nt = 0; nt < 4; ++nt) {
#pragma unroll
    for (int r = 0; r < 4; ++r) {
      op[(q0 + wave * 16 + quad * 4 + r) * D + nt * 16 + l15] = o_acc[nt][r];
    }
  }
}

extern "C" void kernel_launch(void* const* d_in, const int* in_sizes, int n_in,
                              void* d_out, int out_size, void* d_ws, size_t ws_size,
                              hipStream_t stream) {
  const float* q = (const float*)d_in[0];
  const float* k = (const float*)d_in[1];
  const float* v = (const float*)d_in[2];
  const int*   m = (const int*)d_in[3];   // harness promotes bool -> int32
  float* out = (float*)d_out;

  // workspace layout: KB (8.4MB) | VB (8.4MB) | bitmask (16.8MB) — ws is ~2GB
  short* kb = (short*)d_ws;
  short* vb = kb + NKV;
  unsigned long long* mw = (unsigned long long*)(vb + NKV);

  cvt_kv_bf16<<<dim3(2048), dim3(256), 0, stream>>>(k, v, kb, vb);
  mask_pack<<<dim3(2048), dim3(256), 0, stream>>>(m, mw);
  attn_tanh_kernel<<<dim3(1024), dim3(256), 0, stream>>>(q, kb, vb, mw, out);
}

// Round 9
// 784.276 us; speedup vs baseline: 1.0043x; 1.0043x over previous
//
#include <hip/hip_runtime.h>

namespace {

constexpr int N = 2048;
constexpr int D = 64;
constexpr float SCALE = 0.125f;   // D^-0.5
constexpr int LS = 72;            // LDS row stride (shorts): 16B-aligned rows for b128
constexpr int NT = N / 64;        // 32 K-tiles; 32 mask-words per row
constexpr int BH = 32;            // B*H
constexpr size_t NKV    = (size_t)BH * N * D;   // elems per K/V tensor
constexpr size_t NMASK  = (size_t)BH * N * N;
constexpr size_t NWORDS = NMASK / 64;

typedef __attribute__((ext_vector_type(8)))  short bf16x8;   // MFMA A/B frag
typedef __attribute__((ext_vector_type(4)))  short short4v;
typedef __attribute__((ext_vector_type(2)))  short short2v;
typedef __attribute__((ext_vector_type(16))) float f32x16;   // 32x32 MFMA C/D

__device__ inline short f2bf(float x) {
  union { float f; unsigned u; } a; a.f = x;
  unsigned r = a.u + 0x7fffu + ((a.u >> 16) & 1u);
  return (short)(r >> 16);
}

#if __has_builtin(__builtin_amdgcn_cvt_pk_bf16_f32)
typedef __attribute__((ext_vector_type(2))) __bf16 bfv2;
__device__ inline short2v pk_bf(float lo, float hi) {
  bfv2 t = __builtin_amdgcn_cvt_pk_bf16_f32(lo, hi);
  return __builtin_bit_cast(short2v, t);
}
#else
__device__ inline short2v pk_bf(float lo, float hi) {
  short2v r; r[0] = f2bf(lo); r[1] = f2bf(hi); return r;
}
#endif

__device__ inline short4v pk4(float4 f) {
  short2v a = pk_bf(f.x, f.y), b = pk_bf(f.z, f.w);
  short4v r; r[0] = a[0]; r[1] = a[1]; r[2] = b[0]; r[3] = b[1];
  return r;
}

__device__ inline float fast_tanh(float x) {
  float e = __builtin_amdgcn_exp2f(x * 2.885390081777927f);
  return 1.0f - 2.0f * __builtin_amdgcn_rcpf(e + 1.0f);
}

} // namespace

// ---- pre-pass 1a: K fp32 -> bf16 (same layout) ----
__global__ __launch_bounds__(256) void cvt_k_bf16(
    const float* __restrict__ K, short* __restrict__ KB)
{
  const int n4 = (int)(NKV / 4);
  const int stride = gridDim.x * blockDim.x;
  for (int j = blockIdx.x * blockDim.x + threadIdx.x; j < n4; j += stride)
    ((short4v*)KB)[j] = pk4(((const float4*)K)[j]);
}

// ---- pre-pass 1b: V fp32 [bh][kp][d] -> bf16 transposed VT [bh][d][kp] ----
__global__ __launch_bounds__(256) void transpose_v_bf16(
    const float* __restrict__ V, short* __restrict__ VT)
{
  __shared__ short tl[64 * 68];    // [kp_local][d], stride 68 (8B-aligned rows)
  const int tid = threadIdx.x;
  const int bh  = blockIdx.x >> 5;
  const int kp0 = (blockIdx.x & 31) * 64;
  const float* vp = V + ((size_t)bh * N + kp0) * D;
#pragma unroll
  for (int i = 0; i < 4; ++i) {
    int idx = i * 256 + tid;
    int row = idx >> 4, c4 = (idx & 15) << 2;
    *(short4v*)(&tl[row * 68 + c4]) = pk4(*(const float4*)(vp + (size_t)row * D + c4));
  }
  __syncthreads();
  const int d  = tid >> 2;          // 0..63
  const int ch = (tid & 3) * 16;    // kp chunk base
  short* out = VT + (size_t)bh * D * N + (size_t)d * N + kp0 + ch;
  bf16x8 o0, o1;
#pragma unroll
  for (int j = 0; j < 8; ++j) o0[j] = tl[(ch + j) * 68 + d];
#pragma unroll
  for (int j = 0; j < 8; ++j) o1[j] = tl[(ch + 8 + j) * 68 + d];
  *(bf16x8*)(out)     = o0;
  *(bf16x8*)(out + 8) = o1;
}

// ---- pre-pass 2: int32 mask -> 1 bit/elem (streaming at HBM rate) ----
__global__ __launch_bounds__(256) void mask_pack(
    const int* __restrict__ M, unsigned long long* __restrict__ W)
{
  const int lane = threadIdx.x & 63;
  const size_t g = (size_t)blockIdx.x * 4 + (threadIdx.x >> 6);
  const size_t steps = NWORDS / 8192;                 // 256
  const int* p = M + (g * steps) * 64 + lane;
  unsigned long long* w = W + g * steps;
  for (size_t s = 0; s < steps; s += 8) {
    int v[8];
#pragma unroll
    for (int j = 0; j < 8; ++j)
      v[j] = __builtin_nontemporal_load(p + (s + j) * 64);
    unsigned long long b[8];
#pragma unroll
    for (int j = 0; j < 8; ++j) b[j] = __ballot(v[j] != 0);
    if (lane == 0) {
#pragma unroll
      for (int j = 0; j < 8; ++j) w[s + j] = b[j];
    }
  }
}

// ---- main: 64-q-row tile per block, 4 waves, mfma_32x32x16 ----
// Wave w: S-role (sa=w&1 kp-half, sb=w>>1 q-half) computes one 32x32 S^T
// quarter (4 MFMA); PV-role (qh=w&1, dh=w>>1) computes one 32x32 O quadrant
// (4 MFMA). All LDS ops b128 except 4 b64 S-writes. 3 barriers/iter.
__global__ __launch_bounds__(256) void attn_tanh_kernel(
    const float* __restrict__ Q, const short* __restrict__ KB,
    const short* __restrict__ VT, const unsigned long long* __restrict__ MW,
    float* __restrict__ O)
{
  __shared__ __align__(16) short k_s[64 * LS];    // K-tile  [kp][d]
  __shared__ __align__(16) short vt_s[64 * LS];   // V^T-tile [d][kp]
  __shared__ __align__(16) short s_s[64 * LS];    // S       [q][kp]

  const int tid  = threadIdx.x;
  const int wave = tid >> 6;
  const int lane = tid & 63;
  const int l31  = lane & 31;
  const int half = lane >> 5;

  const int sa = wave & 1, sb = wave >> 1;   // S^T quarter: kp-half, q-half
  const int qh = wave & 1, dh = wave >> 1;   // O quadrant: q-half, d-half

  const int bh = blockIdx.x & 31;            // XCD-affine
  const int q0 = (blockIdx.x >> 5) * 64;

  const short* kpb = KB + (size_t)bh * N * D;          // [kp][d]
  const short* vtb = VT + (size_t)bh * D * N;          // [d][kp]
  float* op = O + (size_t)bh * N * D;

  // Q B-fragments for q-half sb: B[k=d][n=q], n=l31 -> q = q0+32sb+l31
  bf16x8 qf[4];
  {
    const float* qrow = Q + ((size_t)bh * N + q0 + 32 * sb + l31) * D;
#pragma unroll
    for (int st = 0; st < 4; ++st) {
      int d0 = 16 * st + 8 * half;
      float4 f0 = *(const float4*)(qrow + d0);
      float4 f1 = *(const float4*)(qrow + d0 + 4);
      short4v lo = pk4(f0), hi = pk4(f1);
      bf16x8 t;
      t[0]=lo[0]; t[1]=lo[1]; t[2]=lo[2]; t[3]=lo[3];
      t[4]=hi[0]; t[5]=hi[1]; t[6]=hi[2]; t[7]=hi[3];
      qf[st] = t;
    }
  }

  const unsigned long long* mwb =
      MW + ((size_t)bh * N + q0 + 32 * sb + l31) * NT;

  const int krow = tid >> 3;         // 0..31 (+32 via i)
  const int kcol = (tid & 7) * 8;
  bf16x8 kreg[2], vreg[2];
  unsigned long long mreg;

  auto issue_loads = [&](int kt1) {
    const short* kp_ = kpb + (size_t)kt1 * 64 * D;
#pragma unroll
    for (int i = 0; i < 2; ++i)
      kreg[i] = *(const bf16x8*)(kp_ + (size_t)(krow + 32 * i) * D + kcol);
#pragma unroll
    for (int i = 0; i < 2; ++i)
      vreg[i] = *(const bf16x8*)(vtb + (size_t)(krow + 32 * i) * N + kt1 * 64 + kcol);
    mreg = mwb[kt1];
  };

  auto write_kv = [&]() {
#pragma unroll
    for (int i = 0; i < 2; ++i)
      *(bf16x8*)(&k_s[(krow + 32 * i) * LS + kcol]) = kreg[i];
#pragma unroll
    for (int i = 0; i < 2; ++i)
      *(bf16x8*)(&vt_s[(krow + 32 * i) * LS + kcol]) = vreg[i];
  };

  issue_loads(0);

  f32x16 o_acc = {};

  for (int kt = 0; kt < NT; ++kt) {
    __syncthreads();                       // B1: prior k_s/vt_s readers done
    write_kv();
    __syncthreads();                       // B2

    const unsigned long long mcur = mreg;
    if (kt + 1 < NT) issue_loads(kt + 1);  // covered by S + B3 + PV

    // ---- S^T quarter = K_half Q_half^T : 4 MFMA ----
    f32x16 sacc = {};
#pragma unroll
    for (int st = 0; st < 4; ++st) {
      bf16x8 a = *(const bf16x8*)(&k_s[(32 * sa + l31) * LS + 16 * st + 8 * half]);
      sacc = __builtin_amdgcn_mfma_f32_32x32x16_bf16(a, qf[st], sacc, 0, 0, 0);
    }
    // C layout (32x32): col = n = q = l31; row = m = kp = (reg&3)+8*(reg>>2)+4*half
#pragma unroll
    for (int g = 0; g < 4; ++g) {
      const int kpb_loc = 32 * sa + 8 * g + 4 * half;
      const unsigned bits = (unsigned)(mcur >> kpb_loc) & 0xFu;
      float s0 = (bits & 1u) ? 0.f : fast_tanh(sacc[4 * g + 0] * SCALE);
      float s1 = (bits & 2u) ? 0.f : fast_tanh(sacc[4 * g + 1] * SCALE);
      float s2 = (bits & 4u) ? 0.f : fast_tanh(sacc[4 * g + 2] * SCALE);
      float s3 = (bits & 8u) ? 0.f : fast_tanh(sacc[4 * g + 3] * SCALE);
      short2v p0 = pk_bf(s0, s1), p1 = pk_bf(s2, s3);
      short4v sv; sv[0]=p0[0]; sv[1]=p0[1]; sv[2]=p1[0]; sv[3]=p1[1];
      *(short4v*)(&s_s[(32 * sb + l31) * LS + kpb_loc]) = sv;
    }
    __syncthreads();                       // B3: s_s cross-wave visible

    // ---- O quadrant += S_half V_half : 4 MFMA ----
#pragma unroll
    for (int st = 0; st < 4; ++st) {
      bf16x8 a = *(const bf16x8*)(&s_s[(32 * qh + l31) * LS + 16 * st + 8 * half]);
      bf16x8 b = *(const bf16x8*)(&vt_s[(32 * dh + l31) * LS + 16 * st + 8 * half]);
      o_acc = __builtin_amdgcn_mfma_f32_32x32x16_bf16(a, b, o_acc, 0, 0, 0);
    }
  }

  // ---- write O: col = d = 32dh+l31; row = q = 32qh+(reg&3)+8*(reg>>2)+4*half ----
#pragma unroll
  for (int reg = 0; reg < 16; ++reg) {
    const int qr = q0 + 32 * qh + (reg & 3) + 8 * (reg >> 2) + 4 * half;
    op[(size_t)qr * D + 32 * dh + l31] = o_acc[reg];
  }
}

extern "C" void kernel_launch(void* const* d_in, const int* in_sizes, int n_in,
                              void* d_out, int out_size, void* d_ws, size_t ws_size,
                              hipStream_t stream) {
  const float* q = (const float*)d_in[0];
  const float* k = (const float*)d_in[1];
  const float* v = (const float*)d_in[2];
  const int*   m = (const int*)d_in[3];
  float* out = (float*)d_out;

  short* kb = (short*)d_ws;
  short* vt = kb + NKV;
  unsigned long long* mw = (unsigned long long*)(vt + NKV);

  cvt_k_bf16<<<dim3(1024), dim3(256), 0, stream>>>(k, kb);
  transpose_v_bf16<<<dim3(1024), dim3(256), 0, stream>>>(v, vt);
  mask_pack<<<dim3(2048), dim3(256), 0, stream>>>(m, mw);
  attn_tanh_kernel<<<dim3(1024), dim3(256), 0, stream>>>(q, kb, vt, mw, out);
}